// Round 1
// baseline (244.998 us; speedup 1.0000x reference)
//
#include <hip/hip_runtime.h>

// Fused: h1 = X @ W^T + b ; h2 = relu(h1 @ RW + 1) ; s0 = sum(h2)
// then n = #halvings of f32(s0) until <= 1 ; out = f32(s0) * 2^-n.
//
// X: (NROWS, 20) fp32, W: (20,20), b: (20,), RW: (20,20).
// One thread handles 2 rows (160 contiguous bytes). W/b/RW staged transposed
// in LDS so per-k columns are contiguous (5x float4 broadcast reads).

#define D 20
#define BLOCK 256

__global__ void __launch_bounds__(BLOCK)
fused_mlp_sum(const float* __restrict__ X,
              const float* __restrict__ W,
              const float* __restrict__ b,
              const float* __restrict__ RW,
              double* __restrict__ acc,
              int nrows) {
    // Transposed copies: sWt[k*20+j] = W[j][k], sRWt[k*20+j] = RW[j][k]
    __shared__ float sWt[D * D];
    __shared__ float sRWt[D * D];
    __shared__ float sb[D];
    __shared__ float wave_sums[BLOCK / 64];

    const int tid = threadIdx.x;
    for (int i = tid; i < D * D; i += BLOCK) {
        int j = i / D, k = i % D;
        sWt[k * D + j]  = W[i];
        sRWt[k * D + j] = RW[i];
    }
    if (tid < D) sb[tid] = b[tid];
    __syncthreads();

    const long long g = (long long)blockIdx.x * BLOCK + tid;
    const long long row0 = g * 2;
    float lsum = 0.0f;

    // nrows is even (2,000,000), so row0 < nrows implies row0+1 < nrows.
    if (row0 < nrows) {
        const float* xp = X + row0 * D;

        float x0[D], x1[D];
#pragma unroll
        for (int q = 0; q < 5; ++q) {
            float4 v = ((const float4*)xp)[q];
            x0[4 * q + 0] = v.x; x0[4 * q + 1] = v.y;
            x0[4 * q + 2] = v.z; x0[4 * q + 3] = v.w;
            float4 u = ((const float4*)(xp + D))[q];
            x1[4 * q + 0] = u.x; x1[4 * q + 1] = u.y;
            x1[4 * q + 2] = u.z; x1[4 * q + 3] = u.w;
        }

        float h0[D], h1[D];
#pragma unroll
        for (int j = 0; j < D; ++j) { h0[j] = sb[j]; h1[j] = sb[j]; }

        // Phase 1: h[j] += W[j][k] * x[k], k outer so W column k (= sWt row k)
        // is a uniform broadcast read shared by both rows.
#pragma unroll
        for (int k = 0; k < D; ++k) {
            float wv[D];
#pragma unroll
            for (int q = 0; q < 5; ++q) {
                float4 v = ((const float4*)(sWt + k * D))[q];
                wv[4 * q + 0] = v.x; wv[4 * q + 1] = v.y;
                wv[4 * q + 2] = v.z; wv[4 * q + 3] = v.w;
            }
            const float a0 = x0[k], a1 = x1[k];
#pragma unroll
            for (int j = 0; j < D; ++j) {
                h0[j] = fmaf(wv[j], a0, h0[j]);
                h1[j] = fmaf(wv[j], a1, h1[j]);
            }
        }

        // Phase 2: t = 1 + sum_j h[j] * RW[j][k]; lsum += relu(t)
#pragma unroll
        for (int k = 0; k < D; ++k) {
            float rv[D];
#pragma unroll
            for (int q = 0; q < 5; ++q) {
                float4 v = ((const float4*)(sRWt + k * D))[q];
                rv[4 * q + 0] = v.x; rv[4 * q + 1] = v.y;
                rv[4 * q + 2] = v.z; rv[4 * q + 3] = v.w;
            }
            float t0 = 1.0f, t1 = 1.0f;
#pragma unroll
            for (int j = 0; j < D; ++j) {
                t0 = fmaf(h0[j], rv[j], t0);
                t1 = fmaf(h1[j], rv[j], t1);
            }
            lsum += fmaxf(t0, 0.0f) + fmaxf(t1, 0.0f);
        }
    }

    // Wave (64-lane) reduction, then block reduction, then one double atomic.
#pragma unroll
    for (int off = 32; off > 0; off >>= 1)
        lsum += __shfl_down(lsum, off, 64);
    if ((tid & 63) == 0) wave_sums[tid >> 6] = lsum;
    __syncthreads();
    if (tid == 0) {
        float bs = 0.0f;
#pragma unroll
        for (int w = 0; w < BLOCK / 64; ++w) bs += wave_sums[w];
        atomicAdd(acc, (double)bs);
    }
}

__global__ void finalize_kernel(const double* __restrict__ acc,
                                float* __restrict__ out) {
    double s0 = acc[0];
    float s = (float)s0;   // reference's s0 is f32
    int n = 0;
    while (s > 1.0f) { ++n; s *= 0.5f; }  // exact power-of-2 halvings
    out[0] = s;            // == f32(s0) * 2^-n
}

extern "C" void kernel_launch(void* const* d_in, const int* in_sizes, int n_in,
                              void* d_out, int out_size, void* d_ws, size_t ws_size,
                              hipStream_t stream) {
    const float* X  = (const float*)d_in[0];
    const float* W  = (const float*)d_in[1];
    const float* b  = (const float*)d_in[2];
    const float* RW = (const float*)d_in[3];
    float* out = (float*)d_out;
    double* acc = (double*)d_ws;

    const int nrows = in_sizes[0] / D;  // 2,000,000

    // d_ws is re-poisoned to 0xAA before every launch — zero the accumulator.
    hipMemsetAsync(d_ws, 0, sizeof(double), stream);

    const int nthreads = (nrows + 1) / 2;           // 2 rows per thread
    const int blocks = (nthreads + BLOCK - 1) / BLOCK;
    fused_mlp_sum<<<blocks, BLOCK, 0, stream>>>(X, W, b, RW, acc, nrows);
    finalize_kernel<<<1, 1, 0, stream>>>(acc, out);
}